// Round 8
// baseline (116.042 us; speedup 1.0000x reference)
//
#include <hip/hip_runtime.h>
#include <hip/hip_fp16.h>

// Problem constants (from reference)
#define NN 50000
#define EE 800000
#define MAXDEG 64           // Poisson(16) max degree; P(deg>64) ~ 1e-18
#define PB_BLOCKS 782       // covers 50048 nodes @64/block and 800768 edges @1024/block

union F4H { float4 f4; __half2 h2[4]; };

__device__ __forceinline__ float lane_bcast(float v, int l) {
    return __int_as_float(__builtin_amdgcn_readlane(__float_as_int(v), l));
}

// ---- macro-unrolled W-register GEMV machinery (NO arrays -> NO scratch) ----
#define REP16(M) M(0) M(1) M(2) M(3) M(4) M(5) M(6) M(7) \
                 M(8) M(9) M(10) M(11) M(12) M(13) M(14) M(15)

#define DECLW(i) float4 wk##i, ws##i;

#define LOADW(i) \
    wk##i.x = Wk[(i*4+0)*64+lane]; wk##i.y = Wk[(i*4+1)*64+lane]; \
    wk##i.z = Wk[(i*4+2)*64+lane]; wk##i.w = Wk[(i*4+3)*64+lane]; \
    ws##i.x = Ws[(i*4+0)*64+lane]; ws##i.y = Ws[(i*4+1)*64+lane]; \
    ws##i.z = Ws[(i*4+2)*64+lane]; ws##i.w = Ws[(i*4+3)*64+lane];

// Pin the loaded W values into VGPRs: the asm "writes" them, so the loop must
// use the register copies — the compiler can no longer sink/rematerialize the
// loads into the node loop (R7's failure: 32KB of W re-read from L1 per node).
#define PINW(i) asm volatile("" : \
    "+v"(wk##i.x), "+v"(wk##i.y), "+v"(wk##i.z), "+v"(wk##i.w), \
    "+v"(ws##i.x), "+v"(ws##i.y), "+v"(ws##i.z), "+v"(ws##i.w));

// 4 k-steps; accumulator selected by i&3 to break the dependency chain
#define FMA4(i) { \
    float f0 = lane_bcast(fv, i*4+0); \
    float f1 = lane_bcast(fv, i*4+1); \
    float f2 = lane_bcast(fv, i*4+2); \
    float f3 = lane_bcast(fv, i*4+3); \
    aK##i##_ = fmaf(f0, wk##i.x, aK##i##_); aS##i##_ = fmaf(f0, ws##i.x, aS##i##_); \
    aK##i##_ = fmaf(f1, wk##i.y, aK##i##_); aS##i##_ = fmaf(f1, ws##i.y, aS##i##_); \
    aK##i##_ = fmaf(f2, wk##i.z, aK##i##_); aS##i##_ = fmaf(f2, ws##i.z, aS##i##_); \
    aK##i##_ = fmaf(f3, wk##i.w, aK##i##_); aS##i##_ = fmaf(f3, ws##i.w, aS##i##_); }

// map macro index to one of 4 accumulators
#define aK0_  aK0
#define aK1_  aK1
#define aK2_  aK2
#define aK3_  aK3
#define aK4_  aK0
#define aK5_  aK1
#define aK6_  aK2
#define aK7_  aK3
#define aK8_  aK0
#define aK9_  aK1
#define aK10_ aK2
#define aK11_ aK3
#define aK12_ aK0
#define aK13_ aK1
#define aK14_ aK2
#define aK15_ aK3
#define aS0_  aS0
#define aS1_  aS1
#define aS2_  aS2
#define aS3_  aS3
#define aS4_  aS0
#define aS5_  aS1
#define aS6_  aS2
#define aS7_  aS3
#define aS8_  aS0
#define aS9_  aS1
#define aS10_ aS2
#define aS11_ aS3
#define aS12_ aS0
#define aS13_ aS1
#define aS14_ aS2
#define aS15_ aS3

// ---------------------------------------------------------------------------
// Fused prep+build. Every block:
//   stage 1: 1024 edges (4/thread): returning atomicAdd cursors (latency
//            drains under stage 2's 128 W loads)
//   stage 2: W columns into 32 NAMED float4 registers (lane = out column),
//            then PINNED via inline-asm keep-alive
//   stage 3: retire the edge scatter stores
//   stage 4: 64 nodes (16/wave): macro-unrolled readlane GEMV + qv fp16 pack
// ---------------------------------------------------------------------------
__global__ __launch_bounds__(256, 2) void prep_build_kernel(
    const float* __restrict__ feat,
    const float* __restrict__ Wk, const float* __restrict__ bk,
    const float* __restrict__ Ws, const float* __restrict__ bs,
    const float* __restrict__ q, const float* __restrict__ v,
    const int* __restrict__ src, const int* __restrict__ dst,
    float* __restrict__ kdst, float* __restrict__ skip,
    __half2* __restrict__ qv, int* __restrict__ count,
    int* __restrict__ sorted_src)
{
    int tid  = threadIdx.x;
    int bid  = blockIdx.x;
    int wave = tid >> 6, lane = tid & 63;

    // ---- stage 1: edge batch, atomics in flight ----
    int ebase = bid * 1024 + tid * 4;      // EE % 4 == 0
    int4 es, ed;
    int p0 = MAXDEG, p1 = MAXDEG, p2 = MAXDEG, p3 = MAXDEG;
    bool ev = ebase < EE;
    if (ev) {
        es = *(const int4*)(src + ebase);
        ed = *(const int4*)(dst + ebase);
        p0 = atomicAdd(count + ed.x, 1);
        p1 = atomicAdd(count + ed.y, 1);
        p2 = atomicAdd(count + ed.z, 1);
        p3 = atomicAdd(count + ed.w, 1);
    }

    // ---- stage 2: W into named registers, pinned ----
    REP16(DECLW)
    REP16(LOADW)
    REP16(PINW)
    float bkc = bk[lane], bsc = bs[lane];

    // ---- stage 3: retire the edge scatter ----
    if (ev) {
        if (p0 < MAXDEG) sorted_src[ed.x * MAXDEG + p0] = es.x;
        if (p1 < MAXDEG) sorted_src[ed.y * MAXDEG + p1] = es.y;
        if (p2 < MAXDEG) sorted_src[ed.z * MAXDEG + p2] = es.z;
        if (p3 < MAXDEG) sorted_src[ed.w * MAXDEG + p3] = es.w;
    }

    // ---- stage 4: node linears (16 nodes per wave) ----
    int base = bid * 64 + wave * 16;
    int cnt  = NN - base;
    if (cnt <= 0) return;
    if (cnt > 16) cnt = 16;

    size_t rb = (size_t)base * 64 + lane;
    float fv = feat[rb];
    float qs = q[rb];
    float vs = v[rb];

    for (int nd = 0; nd < cnt; ++nd) {
        int node = base + nd;
        // software-pipelined lookahead for the next node's rows
        int noden = (node + 1 < NN) ? node + 1 : NN - 1;
        size_t rbn = (size_t)noden * 64 + lane;
        float fvn = feat[rbn];
        float qsn = q[rbn];
        float vsn = v[rbn];

        float aK0 = bkc, aK1 = 0.f, aK2 = 0.f, aK3 = 0.f;
        float aS0 = bsc, aS1 = 0.f, aS2 = 0.f, aS3 = 0.f;
        REP16(FMA4)
        float accK = (aK0 + aK1) + (aK2 + aK3);
        float accS = (aS0 + aS1) + (aS2 + aS3);

        size_t wb = (size_t)node * 64 + lane;
        kdst[wb] = accK;
        skip[wb] = accS;
        qv[wb]   = __floats2half2_rn(qs, vs);

        fv = fvn; qs = qsn; vs = vsn;
    }
}

// ---------------------------------------------------------------------------
// Gather aggregation + epilogue. One 64-lane wave per node.
// Lane layout: g = lane>>4 (edge subslot, 4 edges/iter), w = lane&15 covers
// slots w*4..w*4+3 (slot = h*16+d, so each lane's 4 slots share head h=w>>2).
// softmax shift-invariance -> no segment-max pass (scores are O(5)).
// ---------------------------------------------------------------------------
__global__ __launch_bounds__(256) void gather_finalize_kernel(
    const __half2* __restrict__ qv,        // [N,64] (q,v) pairs
    const float*   __restrict__ kdst,      // [N,64]
    const float*   __restrict__ skipb,     // [N,64]
    const int*     __restrict__ sorted_src,// [N,MAXDEG]
    const int*     __restrict__ deg,       // [N]
    const float*   __restrict__ Wg,        // [192]
    const float*   __restrict__ bg,
    const float*   __restrict__ gamma,
    const float*   __restrict__ beta,
    const float*   __restrict__ prelu_a,
    float* __restrict__ out, int n)
{
    int node = (blockIdx.x * 256 + threadIdx.x) >> 6;
    int lane = threadIdx.x & 63;
    if (node >= n) return;
    int g = lane >> 4;   // which edge of the 4-edge group
    int w = lane & 15;   // slot quartet index

    float4 k4 = *(const float4*)(kdst + (size_t)node * 64 + w * 4);

    int dcount = deg[node];
    if (dcount > MAXDEG) dcount = MAXDEG;
    int s_all = (lane < dcount) ? sorted_src[(size_t)node * MAXDEG + lane] : 0;

    float den = 0.f;
    float acc0 = 0.f, acc1 = 0.f, acc2 = 0.f, acc3 = 0.f;

    int niter = (dcount + 3) >> 2;
    for (int j4 = 0; j4 < niter; ++j4) {
        int e = j4 * 4 + g;
        int s = __shfl(s_all, e & 63);
        F4H r;
        r.f4 = *(const float4*)(qv + (size_t)s * 64 + w * 4);
        float2 p0 = __half22float2(r.h2[0]);
        float2 p1 = __half22float2(r.h2[1]);
        float2 p2 = __half22float2(r.h2[2]);
        float2 p3 = __half22float2(r.h2[3]);
        // partial dot over this lane's 4 slots (all same head)
        float p = p0.x * k4.x + p1.x * k4.y + p2.x * k4.z + p3.x * k4.w;
        // reduce across the 4 lanes of this head cluster
        p += __shfl_xor(p, 1);
        p += __shfl_xor(p, 2);
        float ex = (e < dcount) ? __expf(p * 0.25f) : 0.f;  // 1/sqrt(16)
        den += ex;
        acc0 = fmaf(ex, p0.y, acc0);
        acc1 = fmaf(ex, p1.y, acc1);
        acc2 = fmaf(ex, p2.y, acc2);
        acc3 = fmaf(ex, p3.y, acc3);
    }

    // reduce across the 4 edge-subslot groups
    den  += __shfl_xor(den, 16);  den  += __shfl_xor(den, 32);
    acc0 += __shfl_xor(acc0, 16); acc0 += __shfl_xor(acc0, 32);
    acc1 += __shfl_xor(acc1, 16); acc1 += __shfl_xor(acc1, 32);
    acc2 += __shfl_xor(acc2, 16); acc2 += __shfl_xor(acc2, 32);
    acc3 += __shfl_xor(acc3, 16); acc3 += __shfl_xor(acc3, 32);

    float inv = (den > 0.f) ? 1.f / den : 0.f;
    float r0 = acc0 * inv, r1 = acc1 * inv, r2 = acc2 * inv, r3 = acc3 * inv;

    float4 sk4 = *(const float4*)(skipb + (size_t)node * 64 + w * 4);
    int slot = w * 4;

    // gate: sigmoid([skip, rst, skip-rst] @ Wg + bg)
    float gp = sk4.x * Wg[slot]     + r0 * Wg[64 + slot]     + (sk4.x - r0) * Wg[128 + slot]
             + sk4.y * Wg[slot + 1] + r1 * Wg[64 + slot + 1] + (sk4.y - r1) * Wg[128 + slot + 1]
             + sk4.z * Wg[slot + 2] + r2 * Wg[64 + slot + 2] + (sk4.z - r2) * Wg[128 + slot + 2]
             + sk4.w * Wg[slot + 3] + r3 * Wg[64 + slot + 3] + (sk4.w - r3) * Wg[128 + slot + 3];
    gp += __shfl_xor(gp, 1);
    gp += __shfl_xor(gp, 2);
    gp += __shfl_xor(gp, 4);
    gp += __shfl_xor(gp, 8);
    float gate = 1.f / (1.f + __expf(-(gp + bg[0])));

    float m0 = gate * sk4.x + (1.f - gate) * r0;
    float m1 = gate * sk4.y + (1.f - gate) * r1;
    float m2 = gate * sk4.z + (1.f - gate) * r2;
    float m3 = gate * sk4.w + (1.f - gate) * r3;

    // LayerNorm over 64
    float mu = m0 + m1 + m2 + m3;
    mu += __shfl_xor(mu, 1); mu += __shfl_xor(mu, 2);
    mu += __shfl_xor(mu, 4); mu += __shfl_xor(mu, 8);
    mu *= (1.f / 64.f);
    float d0 = m0 - mu, d1 = m1 - mu, d2 = m2 - mu, d3 = m3 - mu;
    float var = d0 * d0 + d1 * d1 + d2 * d2 + d3 * d3;
    var += __shfl_xor(var, 1); var += __shfl_xor(var, 2);
    var += __shfl_xor(var, 4); var += __shfl_xor(var, 8);
    var *= (1.f / 64.f);
    float rs = rsqrtf(var + 1e-5f);

    float al = prelu_a[0];
    float y0 = d0 * rs * gamma[slot]     + beta[slot];
    float y1 = d1 * rs * gamma[slot + 1] + beta[slot + 1];
    float y2 = d2 * rs * gamma[slot + 2] + beta[slot + 2];
    float y3 = d3 * rs * gamma[slot + 3] + beta[slot + 3];
    y0 = (y0 >= 0.f) ? y0 : al * y0;
    y1 = (y1 >= 0.f) ? y1 : al * y1;
    y2 = (y2 >= 0.f) ? y2 : al * y2;
    y3 = (y3 >= 0.f) ? y3 : al * y3;

    if (g == 0) {
        float4 o; o.x = y0; o.y = y1; o.z = y2; o.w = y3;
        *(float4*)(out + (size_t)node * 64 + slot) = o;
    }
}

// ---------------------------------------------------------------------------
extern "C" void kernel_launch(void* const* d_in, const int* in_sizes, int n_in,
                              void* d_out, int out_size, void* d_ws, size_t ws_size,
                              hipStream_t stream)
{
    const float* q_src  = (const float*)d_in[0];
    const float* v_src  = (const float*)d_in[1];
    const float* feat   = (const float*)d_in[2];
    const int*   src    = (const int*)d_in[3];
    const int*   dst    = (const int*)d_in[4];
    const float* Wk     = (const float*)d_in[5];
    const float* bk     = (const float*)d_in[6];
    const float* Wskip  = (const float*)d_in[7];
    const float* bskip  = (const float*)d_in[8];
    const float* Wgate  = (const float*)d_in[9];
    const float* bgate  = (const float*)d_in[10];
    const float* ln_g   = (const float*)d_in[11];
    const float* ln_b   = (const float*)d_in[12];
    const float* prelu  = (const float*)d_in[13];

    float* out = (float*)d_out;

    // workspace layout
    char* ws = (char*)d_ws;
    float*    kdst       = (float*)(ws);                            // N*64 f
    float*    skip       = (float*)(ws + (size_t)NN * 64 * 4);      // N*64 f
    int*      sorted_src = (int*)  (ws + (size_t)NN * 64 * 4 * 2);  // N*64 i
    __half2*  qv         = (__half2*)(ws + (size_t)NN * 64 * 4 * 3);// N*64 h2
    int*      count      = (int*)  (ws + (size_t)NN * 64 * 4 * 4);  // N i

    hipMemsetAsync(count, 0, (size_t)NN * 4, stream);

    prep_build_kernel<<<PB_BLOCKS, 256, 0, stream>>>(
        feat, Wk, bk, Wskip, bskip, q_src, v_src, src, dst,
        kdst, skip, qv, count, sorted_src);

    int gblk = (NN * 64 + 255) / 256;   // one wave per node
    gather_finalize_kernel<<<gblk, 256, 0, stream>>>(qv, kdst, skip,
                                                     sorted_src, count,
                                                     Wgate, bgate, ln_g, ln_b,
                                                     prelu, out, NN);
}

// Round 9
// 105.104 us; speedup vs baseline: 1.1041x; 1.1041x over previous
//
#include <hip/hip_runtime.h>
#include <hip/hip_fp16.h>

// Problem constants (from reference)
#define NN 50000
#define EE 800000
#define MAXDEG 64           // Poisson(16) max degree; P(deg>64) ~ 1e-18
#define CSTRIDE 16          // count padded: one counter per 64B line (atomic serialization fix)
#define PB_BLOCKS 782       // covers 50048 nodes @64/block and 800768 edges @1024/block

typedef _Float16 f16x8 __attribute__((ext_vector_type(8)));
typedef float    f32x4 __attribute__((ext_vector_type(4)));

union F4H { float4 f4; __half2 h2[4]; };

// ---------------------------------------------------------------------------
// Fused prep+build. Per block:
//   stage 1: 1024 edges (4/thread): returning atomicAdd cursors on PADDED
//            counters (64B apart -> no same-line RMW serialization)
//   stage 2: W (Wk|Ws) -> LDS as f16 in MFMA B-FRAGMENT ORDER:
//            sFrag[(c*2+kt)*64 + lane] = 8 contiguous f16 per lane
//            (contiguous 16B/lane ds_read_b128 = conflict-free)
//   stage 3: retire edge scatter stores
//   stage 4: MFMA linears: each wave = 16 nodes x 128 cols, K=64 via
//            2x mfma_f32_16x16x32_f16 per col-tile, 8 col-tiles
//   stage 5: qv fp16 packing
// ---------------------------------------------------------------------------
__global__ __launch_bounds__(256) void prep_build_kernel(
    const float* __restrict__ feat,
    const float* __restrict__ Wk, const float* __restrict__ bk,
    const float* __restrict__ Ws, const float* __restrict__ bs,
    const float* __restrict__ q, const float* __restrict__ v,
    const int* __restrict__ src, const int* __restrict__ dst,
    float* __restrict__ kdst, float* __restrict__ skip,
    __half2* __restrict__ qv, int* __restrict__ count,
    int* __restrict__ sorted_src)
{
    __shared__ f16x8 sFrag[16 * 64];   // 16 KB: [(coltile*2 + ktile)*64 + lane]

    int tid = threadIdx.x, bid = blockIdx.x;
    int wave = tid >> 6, lane = tid & 63;

    // ---- stage 1: edge batch, atomics in flight ----
    int ebase = bid * 1024 + tid * 4;      // EE % 4 == 0
    int4 es, ed;
    int p0 = MAXDEG, p1 = MAXDEG, p2 = MAXDEG, p3 = MAXDEG;
    bool ev = ebase < EE;
    if (ev) {
        es = *(const int4*)(src + ebase);
        ed = *(const int4*)(dst + ebase);
        p0 = atomicAdd(count + ed.x * CSTRIDE, 1);
        p1 = atomicAdd(count + ed.y * CSTRIDE, 1);
        p2 = atomicAdd(count + ed.z * CSTRIDE, 1);
        p3 = atomicAdd(count + ed.w * CSTRIDE, 1);
    }

    // ---- stage 2: W -> LDS f16 fragment-order ----
    // element (k, n): ktile = k>>5, lane = ((k>>3)&3)*16 + (n&15), j = k&7,
    // coltile = n>>4 (Wk: n = nk, Ws: n = 64 + nk)
    for (int i = tid; i < 4096; i += 256) {
        int k = i >> 6, nk = i & 63;
        int kt = k >> 5, j = k & 7;
        int lf = ((k >> 3) & 3) * 16 + (nk & 15);
        ((_Float16*)&sFrag[((nk >> 4) * 2 + kt) * 64 + lf])[j]       = (_Float16)Wk[i];
        ((_Float16*)&sFrag[((4 + (nk >> 4)) * 2 + kt) * 64 + lf])[j] = (_Float16)Ws[i];
    }

    // ---- stage 3: retire the edge scatter ----
    if (ev) {
        if (p0 < MAXDEG) sorted_src[ed.x * MAXDEG + p0] = es.x;
        if (p1 < MAXDEG) sorted_src[ed.y * MAXDEG + p1] = es.y;
        if (p2 < MAXDEG) sorted_src[ed.z * MAXDEG + p2] = es.z;
        if (p3 < MAXDEG) sorted_src[ed.w * MAXDEG + p3] = es.w;
    }

    __syncthreads();

    // ---- stage 4: MFMA linears. NN % 16 == 0 -> node tiles all-or-nothing ----
    int base16 = bid * 64 + wave * 16;
    if (base16 < NN) {
        int m = lane & 15;                    // A row (node) / D col key
        int kg = lane >> 4;                   // k-octet group
        const float* arow = feat + (size_t)(base16 + m) * 64 + kg * 8;
        float4 fa0 = *(const float4*)(arow + 0);
        float4 fa1 = *(const float4*)(arow + 4);
        float4 fa2 = *(const float4*)(arow + 32);
        float4 fa3 = *(const float4*)(arow + 36);
        f16x8 a0 = { (_Float16)fa0.x,(_Float16)fa0.y,(_Float16)fa0.z,(_Float16)fa0.w,
                     (_Float16)fa1.x,(_Float16)fa1.y,(_Float16)fa1.z,(_Float16)fa1.w };
        f16x8 a1 = { (_Float16)fa2.x,(_Float16)fa2.y,(_Float16)fa2.z,(_Float16)fa2.w,
                     (_Float16)fa3.x,(_Float16)fa3.y,(_Float16)fa3.z,(_Float16)fa3.w };

        f32x4 acc0={0,0,0,0}, acc1={0,0,0,0}, acc2={0,0,0,0}, acc3={0,0,0,0};
        f32x4 acc4={0,0,0,0}, acc5={0,0,0,0}, acc6={0,0,0,0}, acc7={0,0,0,0};

#define COLT(c, ACC) { \
        f16x8 b0 = sFrag[((c)*2 + 0) * 64 + lane]; \
        f16x8 b1 = sFrag[((c)*2 + 1) * 64 + lane]; \
        ACC = __builtin_amdgcn_mfma_f32_16x16x32_f16(a0, b0, ACC, 0, 0, 0); \
        ACC = __builtin_amdgcn_mfma_f32_16x16x32_f16(a1, b1, ACC, 0, 0, 0); }

        COLT(0, acc0) COLT(1, acc1) COLT(2, acc2) COLT(3, acc3)
        COLT(4, acc4) COLT(5, acc5) COLT(6, acc6) COLT(7, acc7)
#undef COLT

        int rbase = base16 + (lane >> 4) * 4;   // D row = (lane>>4)*4 + reg

#define STOREC(P, COFF, BIAS, ACC) { \
        int col = (COFF) + m; float bb = BIAS[col]; \
        P[(size_t)(rbase + 0) * 64 + col] = ACC[0] + bb; \
        P[(size_t)(rbase + 1) * 64 + col] = ACC[1] + bb; \
        P[(size_t)(rbase + 2) * 64 + col] = ACC[2] + bb; \
        P[(size_t)(rbase + 3) * 64 + col] = ACC[3] + bb; }

        STOREC(kdst,  0, bk, acc0) STOREC(kdst, 16, bk, acc1)
        STOREC(kdst, 32, bk, acc2) STOREC(kdst, 48, bk, acc3)
        STOREC(skip,  0, bs, acc4) STOREC(skip, 16, bs, acc5)
        STOREC(skip, 32, bs, acc6) STOREC(skip, 48, bs, acc7)
#undef STOREC
    }

    // ---- stage 5: qv fp16 pack (16 half2 per thread, within one node row) ----
    {
        size_t g0 = (size_t)bid * 4096 + (size_t)tid * 16;
        int node = (int)(g0 >> 6);
        if (node < NN) {
            const float4* qp = (const float4*)(q + g0);
            const float4* vp = (const float4*)(v + g0);
            #pragma unroll
            for (int gI = 0; gI < 4; ++gI) {
                float4 qq = qp[gI], vv = vp[gI];
                F4H outw;
                outw.h2[0] = __floats2half2_rn(qq.x, vv.x);
                outw.h2[1] = __floats2half2_rn(qq.y, vv.y);
                outw.h2[2] = __floats2half2_rn(qq.z, vv.z);
                outw.h2[3] = __floats2half2_rn(qq.w, vv.w);
                *(float4*)(qv + g0 + gI * 4) = outw.f4;
            }
        }
    }
}

// ---------------------------------------------------------------------------
// Gather aggregation + epilogue. One 64-lane wave per node.
// Lane layout: g = lane>>4 (edge subslot, 4 edges/iter), w = lane&15 covers
// slots w*4..w*4+3 (slot = h*16+d, so each lane's 4 slots share head h=w>>2).
// softmax shift-invariance -> no segment-max pass (scores are O(5)).
// ---------------------------------------------------------------------------
__global__ __launch_bounds__(256) void gather_finalize_kernel(
    const __half2* __restrict__ qv,        // [N,64] (q,v) pairs
    const float*   __restrict__ kdst,      // [N,64]
    const float*   __restrict__ skipb,     // [N,64]
    const int*     __restrict__ sorted_src,// [N,MAXDEG]
    const int*     __restrict__ deg,       // [N*CSTRIDE], padded
    const float*   __restrict__ Wg,        // [192]
    const float*   __restrict__ bg,
    const float*   __restrict__ gamma,
    const float*   __restrict__ beta,
    const float*   __restrict__ prelu_a,
    float* __restrict__ out, int n)
{
    int node = (blockIdx.x * 256 + threadIdx.x) >> 6;
    int lane = threadIdx.x & 63;
    if (node >= n) return;
    int g = lane >> 4;   // which edge of the 4-edge group
    int w = lane & 15;   // slot quartet index

    float4 k4 = *(const float4*)(kdst + (size_t)node * 64 + w * 4);

    int dcount = deg[(size_t)node * CSTRIDE];
    if (dcount > MAXDEG) dcount = MAXDEG;
    int s_all = (lane < dcount) ? sorted_src[(size_t)node * MAXDEG + lane] : 0;

    float den = 0.f;
    float acc0 = 0.f, acc1 = 0.f, acc2 = 0.f, acc3 = 0.f;

    int niter = (dcount + 3) >> 2;
    for (int j4 = 0; j4 < niter; ++j4) {
        int e = j4 * 4 + g;
        int s = __shfl(s_all, e & 63);
        F4H r;
        r.f4 = *(const float4*)(qv + (size_t)s * 64 + w * 4);
        float2 p0 = __half22float2(r.h2[0]);
        float2 p1 = __half22float2(r.h2[1]);
        float2 p2 = __half22float2(r.h2[2]);
        float2 p3 = __half22float2(r.h2[3]);
        // partial dot over this lane's 4 slots (all same head)
        float p = p0.x * k4.x + p1.x * k4.y + p2.x * k4.z + p3.x * k4.w;
        // reduce across the 4 lanes of this head cluster
        p += __shfl_xor(p, 1);
        p += __shfl_xor(p, 2);
        float ex = (e < dcount) ? __expf(p * 0.25f) : 0.f;  // 1/sqrt(16)
        den += ex;
        acc0 = fmaf(ex, p0.y, acc0);
        acc1 = fmaf(ex, p1.y, acc1);
        acc2 = fmaf(ex, p2.y, acc2);
        acc3 = fmaf(ex, p3.y, acc3);
    }

    // reduce across the 4 edge-subslot groups
    den  += __shfl_xor(den, 16);  den  += __shfl_xor(den, 32);
    acc0 += __shfl_xor(acc0, 16); acc0 += __shfl_xor(acc0, 32);
    acc1 += __shfl_xor(acc1, 16); acc1 += __shfl_xor(acc1, 32);
    acc2 += __shfl_xor(acc2, 16); acc2 += __shfl_xor(acc2, 32);
    acc3 += __shfl_xor(acc3, 16); acc3 += __shfl_xor(acc3, 32);

    float inv = (den > 0.f) ? 1.f / den : 0.f;
    float r0 = acc0 * inv, r1 = acc1 * inv, r2 = acc2 * inv, r3 = acc3 * inv;

    float4 sk4 = *(const float4*)(skipb + (size_t)node * 64 + w * 4);
    int slot = w * 4;

    // gate: sigmoid([skip, rst, skip-rst] @ Wg + bg)
    float gp = sk4.x * Wg[slot]     + r0 * Wg[64 + slot]     + (sk4.x - r0) * Wg[128 + slot]
             + sk4.y * Wg[slot + 1] + r1 * Wg[64 + slot + 1] + (sk4.y - r1) * Wg[128 + slot + 1]
             + sk4.z * Wg[slot + 2] + r2 * Wg[64 + slot + 2] + (sk4.z - r2) * Wg[128 + slot + 2]
             + sk4.w * Wg[slot + 3] + r3 * Wg[64 + slot + 3] + (sk4.w - r3) * Wg[128 + slot + 3];
    gp += __shfl_xor(gp, 1);
    gp += __shfl_xor(gp, 2);
    gp += __shfl_xor(gp, 4);
    gp += __shfl_xor(gp, 8);
    float gate = 1.f / (1.f + __expf(-(gp + bg[0])));

    float m0 = gate * sk4.x + (1.f - gate) * r0;
    float m1 = gate * sk4.y + (1.f - gate) * r1;
    float m2 = gate * sk4.z + (1.f - gate) * r2;
    float m3 = gate * sk4.w + (1.f - gate) * r3;

    // LayerNorm over 64
    float mu = m0 + m1 + m2 + m3;
    mu += __shfl_xor(mu, 1); mu += __shfl_xor(mu, 2);
    mu += __shfl_xor(mu, 4); mu += __shfl_xor(mu, 8);
    mu *= (1.f / 64.f);
    float d0 = m0 - mu, d1 = m1 - mu, d2 = m2 - mu, d3 = m3 - mu;
    float var = d0 * d0 + d1 * d1 + d2 * d2 + d3 * d3;
    var += __shfl_xor(var, 1); var += __shfl_xor(var, 2);
    var += __shfl_xor(var, 4); var += __shfl_xor(var, 8);
    var *= (1.f / 64.f);
    float rs = rsqrtf(var + 1e-5f);

    float al = prelu_a[0];
    float y0 = d0 * rs * gamma[slot]     + beta[slot];
    float y1 = d1 * rs * gamma[slot + 1] + beta[slot + 1];
    float y2 = d2 * rs * gamma[slot + 2] + beta[slot + 2];
    float y3 = d3 * rs * gamma[slot + 3] + beta[slot + 3];
    y0 = (y0 >= 0.f) ? y0 : al * y0;
    y1 = (y1 >= 0.f) ? y1 : al * y1;
    y2 = (y2 >= 0.f) ? y2 : al * y2;
    y3 = (y3 >= 0.f) ? y3 : al * y3;

    if (g == 0) {
        float4 o; o.x = y0; o.y = y1; o.z = y2; o.w = y3;
        *(float4*)(out + (size_t)node * 64 + slot) = o;
    }
}

// ---------------------------------------------------------------------------
extern "C" void kernel_launch(void* const* d_in, const int* in_sizes, int n_in,
                              void* d_out, int out_size, void* d_ws, size_t ws_size,
                              hipStream_t stream)
{
    const float* q_src  = (const float*)d_in[0];
    const float* v_src  = (const float*)d_in[1];
    const float* feat   = (const float*)d_in[2];
    const int*   src    = (const int*)d_in[3];
    const int*   dst    = (const int*)d_in[4];
    const float* Wk     = (const float*)d_in[5];
    const float* bk     = (const float*)d_in[6];
    const float* Wskip  = (const float*)d_in[7];
    const float* bskip  = (const float*)d_in[8];
    const float* Wgate  = (const float*)d_in[9];
    const float* bgate  = (const float*)d_in[10];
    const float* ln_g   = (const float*)d_in[11];
    const float* ln_b   = (const float*)d_in[12];
    const float* prelu  = (const float*)d_in[13];

    float* out = (float*)d_out;

    // workspace layout
    char* ws = (char*)d_ws;
    const size_t A = (size_t)NN * 64 * 4;            // 12.8 MB unit
    float*    kdst       = (float*)(ws);             // N*64 f
    float*    skip       = (float*)(ws + A);         // N*64 f
    int*      sorted_src = (int*)  (ws + 2 * A);     // N*64 i
    __half2*  qv         = (__half2*)(ws + 3 * A);   // N*64 h2
    int*      count      = (int*)  (ws + 4 * A);     // N*CSTRIDE i (padded)

    hipMemsetAsync(count, 0, (size_t)NN * CSTRIDE * 4, stream);

    prep_build_kernel<<<PB_BLOCKS, 256, 0, stream>>>(
        feat, Wk, bk, Wskip, bskip, q_src, v_src, src, dst,
        kdst, skip, qv, count, sorted_src);

    int gblk = (NN * 64 + 255) / 256;   // one wave per node
    gather_finalize_kernel<<<gblk, 256, 0, stream>>>(qv, kdst, skip,
                                                     sorted_src, count,
                                                     Wgate, bgate, ln_g, ln_b,
                                                     prelu, out, NN);
}

// Round 10
// 101.715 us; speedup vs baseline: 1.1409x; 1.0333x over previous
//
#include <hip/hip_runtime.h>
#include <hip/hip_fp16.h>

// Problem constants (from reference)
#define NN 50000
#define EE 800000
#define MAXDEG 64           // Poisson(16) max degree; P(deg>64) ~ 1e-18
#define CSTRIDE 16          // count padded: one counter per 64B line
#define PB_BLOCKS 782       // covers 50048 nodes @64/block and 800768 edges @1024/block

typedef _Float16 f16x8 __attribute__((ext_vector_type(8)));
typedef float    f32x4 __attribute__((ext_vector_type(4)));

union F4H { float4 f4; __half2 h2[4]; };

// ---------------------------------------------------------------------------
// Fused prep+build. Per block:
//   stage 1: 1024 edges (4/thread): returning atomicAdd cursors (padded)
//   stage 2: W (Wk|Ws) -> LDS f16 in MFMA B-fragment order
//   stage 3: MFMA linears (16 nodes x 128 cols per wave)
//   stage 4: qv fp16 packing
//   stage 5 (LAST): retire edge scatter — atomics drain under stages 2-4
// ---------------------------------------------------------------------------
__global__ __launch_bounds__(256) void prep_build_kernel(
    const float* __restrict__ feat,
    const float* __restrict__ Wk, const float* __restrict__ bk,
    const float* __restrict__ Ws, const float* __restrict__ bs,
    const float* __restrict__ q, const float* __restrict__ v,
    const int* __restrict__ src, const int* __restrict__ dst,
    float* __restrict__ kdst, float* __restrict__ skip,
    __half2* __restrict__ qv, int* __restrict__ count,
    int* __restrict__ sorted_src)
{
    __shared__ f16x8 sFrag[16 * 64];   // 16 KB: [(coltile*2 + ktile)*64 + lane]

    int tid = threadIdx.x, bid = blockIdx.x;
    int wave = tid >> 6, lane = tid & 63;

    // ---- stage 1: edge batch, atomics in flight ----
    int ebase = bid * 1024 + tid * 4;      // EE % 4 == 0
    int4 es, ed;
    int p0 = MAXDEG, p1 = MAXDEG, p2 = MAXDEG, p3 = MAXDEG;
    bool ev = ebase < EE;
    if (ev) {
        es = *(const int4*)(src + ebase);
        ed = *(const int4*)(dst + ebase);
        p0 = atomicAdd(count + ed.x * CSTRIDE, 1);
        p1 = atomicAdd(count + ed.y * CSTRIDE, 1);
        p2 = atomicAdd(count + ed.z * CSTRIDE, 1);
        p3 = atomicAdd(count + ed.w * CSTRIDE, 1);
    }

    // ---- stage 2: W -> LDS f16 fragment-order ----
    for (int i = tid; i < 4096; i += 256) {
        int k = i >> 6, nk = i & 63;
        int kt = k >> 5, j = k & 7;
        int lf = ((k >> 3) & 3) * 16 + (nk & 15);
        ((_Float16*)&sFrag[((nk >> 4) * 2 + kt) * 64 + lf])[j]       = (_Float16)Wk[i];
        ((_Float16*)&sFrag[((4 + (nk >> 4)) * 2 + kt) * 64 + lf])[j] = (_Float16)Ws[i];
    }

    __syncthreads();

    // ---- stage 3: MFMA linears. NN % 16 == 0 -> node tiles all-or-nothing ----
    int base16 = bid * 64 + wave * 16;
    if (base16 < NN) {
        int m = lane & 15;                    // A row (node) / D col key
        int kg = lane >> 4;                   // k-octet group
        const float* arow = feat + (size_t)(base16 + m) * 64 + kg * 8;
        float4 fa0 = *(const float4*)(arow + 0);
        float4 fa1 = *(const float4*)(arow + 4);
        float4 fa2 = *(const float4*)(arow + 32);
        float4 fa3 = *(const float4*)(arow + 36);
        f16x8 a0 = { (_Float16)fa0.x,(_Float16)fa0.y,(_Float16)fa0.z,(_Float16)fa0.w,
                     (_Float16)fa1.x,(_Float16)fa1.y,(_Float16)fa1.z,(_Float16)fa1.w };
        f16x8 a1 = { (_Float16)fa2.x,(_Float16)fa2.y,(_Float16)fa2.z,(_Float16)fa2.w,
                     (_Float16)fa3.x,(_Float16)fa3.y,(_Float16)fa3.z,(_Float16)fa3.w };

        f32x4 acc0={0,0,0,0}, acc1={0,0,0,0}, acc2={0,0,0,0}, acc3={0,0,0,0};
        f32x4 acc4={0,0,0,0}, acc5={0,0,0,0}, acc6={0,0,0,0}, acc7={0,0,0,0};

#define COLT(c, ACC) { \
        f16x8 b0 = sFrag[((c)*2 + 0) * 64 + lane]; \
        f16x8 b1 = sFrag[((c)*2 + 1) * 64 + lane]; \
        ACC = __builtin_amdgcn_mfma_f32_16x16x32_f16(a0, b0, ACC, 0, 0, 0); \
        ACC = __builtin_amdgcn_mfma_f32_16x16x32_f16(a1, b1, ACC, 0, 0, 0); }

        COLT(0, acc0) COLT(1, acc1) COLT(2, acc2) COLT(3, acc3)
        COLT(4, acc4) COLT(5, acc5) COLT(6, acc6) COLT(7, acc7)
#undef COLT

        int rbase = base16 + (lane >> 4) * 4;   // D row = (lane>>4)*4 + reg

#define STOREC(P, COFF, BIAS, ACC) { \
        int col = (COFF) + m; float bb = BIAS[col]; \
        P[(size_t)(rbase + 0) * 64 + col] = ACC[0] + bb; \
        P[(size_t)(rbase + 1) * 64 + col] = ACC[1] + bb; \
        P[(size_t)(rbase + 2) * 64 + col] = ACC[2] + bb; \
        P[(size_t)(rbase + 3) * 64 + col] = ACC[3] + bb; }

        STOREC(kdst,  0, bk, acc0) STOREC(kdst, 16, bk, acc1)
        STOREC(kdst, 32, bk, acc2) STOREC(kdst, 48, bk, acc3)
        STOREC(skip,  0, bs, acc4) STOREC(skip, 16, bs, acc5)
        STOREC(skip, 32, bs, acc6) STOREC(skip, 48, bs, acc7)
#undef STOREC
    }

    // ---- stage 4: qv fp16 pack (16 half2 per thread) ----
    {
        size_t g0 = (size_t)bid * 4096 + (size_t)tid * 16;
        int node = (int)(g0 >> 6);
        if (node < NN) {
            const float4* qp = (const float4*)(q + g0);
            const float4* vp = (const float4*)(v + g0);
            #pragma unroll
            for (int gI = 0; gI < 4; ++gI) {
                float4 qq = qp[gI], vv = vp[gI];
                F4H outw;
                outw.h2[0] = __floats2half2_rn(qq.x, vv.x);
                outw.h2[1] = __floats2half2_rn(qq.y, vv.y);
                outw.h2[2] = __floats2half2_rn(qq.z, vv.z);
                outw.h2[3] = __floats2half2_rn(qq.w, vv.w);
                *(float4*)(qv + g0 + gI * 4) = outw.f4;
            }
        }
    }

    // ---- stage 5: retire the edge scatter (atomics drained under 2-4) ----
    if (ev) {
        if (p0 < MAXDEG) sorted_src[ed.x * MAXDEG + p0] = es.x;
        if (p1 < MAXDEG) sorted_src[ed.y * MAXDEG + p1] = es.y;
        if (p2 < MAXDEG) sorted_src[ed.z * MAXDEG + p2] = es.z;
        if (p3 < MAXDEG) sorted_src[ed.w * MAXDEG + p3] = es.w;
    }
}

// ---------------------------------------------------------------------------
// Gather aggregation + epilogue. One 64-lane wave per node.
// Lane layout: g = lane>>4, w = lane&15 covers slots w*4..w*4+3.
// 8 edges per iteration (two streams per lane: e = it*8+g and it*8+4+g),
// 1-deep software prefetch -> 4 gathers in flight per lane.
// softmax shift-invariance -> no segment-max pass (scores are O(5)).
// ---------------------------------------------------------------------------
__global__ __launch_bounds__(256) void gather_finalize_kernel(
    const __half2* __restrict__ qv,        // [N,64] (q,v) pairs
    const float*   __restrict__ kdst,      // [N,64]
    const float*   __restrict__ skipb,     // [N,64]
    const int*     __restrict__ sorted_src,// [N,MAXDEG]
    const int*     __restrict__ deg,       // [N*CSTRIDE], padded
    const float*   __restrict__ Wg,        // [192]
    const float*   __restrict__ bg,
    const float*   __restrict__ gamma,
    const float*   __restrict__ beta,
    const float*   __restrict__ prelu_a,
    float* __restrict__ out, int n)
{
    int node = (blockIdx.x * 256 + threadIdx.x) >> 6;
    int lane = threadIdx.x & 63;
    if (node >= n) return;
    int g = lane >> 4;   // edge sub-stream
    int w = lane & 15;   // slot quartet index
    int slot = w * 4;

    // hoisted epilogue operands (overlap with the gather loop)
    float4 k4  = *(const float4*)(kdst  + (size_t)node * 64 + slot);
    float4 sk4 = *(const float4*)(skipb + (size_t)node * 64 + slot);
    float wg0a = Wg[slot],      wg1a = Wg[slot+1],      wg2a = Wg[slot+2],      wg3a = Wg[slot+3];
    float wg0b = Wg[64+slot],   wg1b = Wg[64+slot+1],   wg2b = Wg[64+slot+2],   wg3b = Wg[64+slot+3];
    float wg0c = Wg[128+slot],  wg1c = Wg[128+slot+1],  wg2c = Wg[128+slot+2],  wg3c = Wg[128+slot+3];
    float gm0 = gamma[slot], gm1 = gamma[slot+1], gm2 = gamma[slot+2], gm3 = gamma[slot+3];
    float bt0 = beta[slot],  bt1 = beta[slot+1],  bt2 = beta[slot+2],  bt3 = beta[slot+3];
    float bgv = bg[0];
    float al  = prelu_a[0];

    int dcount = deg[(size_t)node * CSTRIDE];
    if (dcount > MAXDEG) dcount = MAXDEG;
    int s_all = (lane < dcount) ? sorted_src[(size_t)node * MAXDEG + lane] : 0;

    float den = 0.f;
    float acc0 = 0.f, acc1 = 0.f, acc2 = 0.f, acc3 = 0.f;

    int niter = (dcount + 7) >> 3;
    if (niter > 0) {
        int sA = __shfl(s_all, g);
        int sB = __shfl(s_all, 4 + g);
        F4H rA, rB;
        rA.f4 = *(const float4*)(qv + (size_t)sA * 64 + slot);
        rB.f4 = *(const float4*)(qv + (size_t)sB * 64 + slot);

        for (int it = 0; it < niter; ++it) {
            F4H cA = rA, cB = rB;
            int eA = it * 8 + g;
            int eB = it * 8 + 4 + g;
            if (it + 1 < niter) {
                int sA2 = __shfl(s_all, (it * 8 + 8 + g) & 63);
                int sB2 = __shfl(s_all, (it * 8 + 12 + g) & 63);
                rA.f4 = *(const float4*)(qv + (size_t)sA2 * 64 + slot);
                rB.f4 = *(const float4*)(qv + (size_t)sB2 * 64 + slot);
            }

            float2 a0 = __half22float2(cA.h2[0]);
            float2 a1 = __half22float2(cA.h2[1]);
            float2 a2 = __half22float2(cA.h2[2]);
            float2 a3 = __half22float2(cA.h2[3]);
            float pA = a0.x * k4.x + a1.x * k4.y + a2.x * k4.z + a3.x * k4.w;
            pA += __shfl_xor(pA, 1);
            pA += __shfl_xor(pA, 2);
            float exA = (eA < dcount) ? __expf(pA * 0.25f) : 0.f;
            den += exA;
            acc0 = fmaf(exA, a0.y, acc0);
            acc1 = fmaf(exA, a1.y, acc1);
            acc2 = fmaf(exA, a2.y, acc2);
            acc3 = fmaf(exA, a3.y, acc3);

            float2 b0 = __half22float2(cB.h2[0]);
            float2 b1 = __half22float2(cB.h2[1]);
            float2 b2 = __half22float2(cB.h2[2]);
            float2 b3 = __half22float2(cB.h2[3]);
            float pB = b0.x * k4.x + b1.x * k4.y + b2.x * k4.z + b3.x * k4.w;
            pB += __shfl_xor(pB, 1);
            pB += __shfl_xor(pB, 2);
            float exB = (eB < dcount) ? __expf(pB * 0.25f) : 0.f;
            den += exB;
            acc0 = fmaf(exB, b0.y, acc0);
            acc1 = fmaf(exB, b1.y, acc1);
            acc2 = fmaf(exB, b2.y, acc2);
            acc3 = fmaf(exB, b3.y, acc3);
        }
    }

    // reduce across the 4 edge-stream groups
    den  += __shfl_xor(den, 16);  den  += __shfl_xor(den, 32);
    acc0 += __shfl_xor(acc0, 16); acc0 += __shfl_xor(acc0, 32);
    acc1 += __shfl_xor(acc1, 16); acc1 += __shfl_xor(acc1, 32);
    acc2 += __shfl_xor(acc2, 16); acc2 += __shfl_xor(acc2, 32);
    acc3 += __shfl_xor(acc3, 16); acc3 += __shfl_xor(acc3, 32);

    float inv = (den > 0.f) ? 1.f / den : 0.f;
    float r0 = acc0 * inv, r1 = acc1 * inv, r2 = acc2 * inv, r3 = acc3 * inv;

    // gate: sigmoid([skip, rst, skip-rst] @ Wg + bg)
    float gp = sk4.x * wg0a + r0 * wg0b + (sk4.x - r0) * wg0c
             + sk4.y * wg1a + r1 * wg1b + (sk4.y - r1) * wg1c
             + sk4.z * wg2a + r2 * wg2b + (sk4.z - r2) * wg2c
             + sk4.w * wg3a + r3 * wg3b + (sk4.w - r3) * wg3c;
    gp += __shfl_xor(gp, 1);
    gp += __shfl_xor(gp, 2);
    gp += __shfl_xor(gp, 4);
    gp += __shfl_xor(gp, 8);
    float gate = 1.f / (1.f + __expf(-(gp + bgv)));

    float m0 = gate * sk4.x + (1.f - gate) * r0;
    float m1 = gate * sk4.y + (1.f - gate) * r1;
    float m2 = gate * sk4.z + (1.f - gate) * r2;
    float m3 = gate * sk4.w + (1.f - gate) * r3;

    // LayerNorm over 64
    float mu = m0 + m1 + m2 + m3;
    mu += __shfl_xor(mu, 1); mu += __shfl_xor(mu, 2);
    mu += __shfl_xor(mu, 4); mu += __shfl_xor(mu, 8);
    mu *= (1.f / 64.f);
    float d0 = m0 - mu, d1 = m1 - mu, d2 = m2 - mu, d3 = m3 - mu;
    float var = d0 * d0 + d1 * d1 + d2 * d2 + d3 * d3;
    var += __shfl_xor(var, 1); var += __shfl_xor(var, 2);
    var += __shfl_xor(var, 4); var += __shfl_xor(var, 8);
    var *= (1.f / 64.f);
    float rs = rsqrtf(var + 1e-5f);

    float y0 = d0 * rs * gm0 + bt0;
    float y1 = d1 * rs * gm1 + bt1;
    float y2 = d2 * rs * gm2 + bt2;
    float y3 = d3 * rs * gm3 + bt3;
    y0 = (y0 >= 0.f) ? y0 : al * y0;
    y1 = (y1 >= 0.f) ? y1 : al * y1;
    y2 = (y2 >= 0.f) ? y2 : al * y2;
    y3 = (y3 >= 0.f) ? y3 : al * y3;

    if (g == 0) {
        float4 o; o.x = y0; o.y = y1; o.z = y2; o.w = y3;
        *(float4*)(out + (size_t)node * 64 + slot) = o;
    }
}

// ---------------------------------------------------------------------------
extern "C" void kernel_launch(void* const* d_in, const int* in_sizes, int n_in,
                              void* d_out, int out_size, void* d_ws, size_t ws_size,
                              hipStream_t stream)
{
    const float* q_src  = (const float*)d_in[0];
    const float* v_src  = (const float*)d_in[1];
    const float* feat   = (const float*)d_in[2];
    const int*   src    = (const int*)d_in[3];
    const int*   dst    = (const int*)d_in[4];
    const float* Wk     = (const float*)d_in[5];
    const float* bk     = (const float*)d_in[6];
    const float* Wskip  = (const float*)d_in[7];
    const float* bskip  = (const float*)d_in[8];
    const float* Wgate  = (const float*)d_in[9];
    const float* bgate  = (const float*)d_in[10];
    const float* ln_g   = (const float*)d_in[11];
    const float* ln_b   = (const float*)d_in[12];
    const float* prelu  = (const float*)d_in[13];

    float* out = (float*)d_out;

    // workspace layout
    char* ws = (char*)d_ws;
    const size_t A = (size_t)NN * 64 * 4;            // 12.8 MB unit
    float*    kdst       = (float*)(ws);             // N*64 f
    float*    skip       = (float*)(ws + A);         // N*64 f
    int*      sorted_src = (int*)  (ws + 2 * A);     // N*64 i
    __half2*  qv         = (__half2*)(ws + 3 * A);   // N*64 h2
    int*      count      = (int*)  (ws + 4 * A);     // N*CSTRIDE i (padded)

    hipMemsetAsync(count, 0, (size_t)NN * CSTRIDE * 4, stream);

    prep_build_kernel<<<PB_BLOCKS, 256, 0, stream>>>(
        feat, Wk, bk, Wskip, bskip, q_src, v_src, src, dst,
        kdst, skip, qv, count, sorted_src);

    int gblk = (NN * 64 + 255) / 256;   // one wave per node
    gather_finalize_kernel<<<gblk, 256, 0, stream>>>(qv, kdst, skip,
                                                     sorted_src, count,
                                                     Wgate, bgate, ln_g, ln_b,
                                                     prelu, out, NN);
}

// Round 11
// 96.046 us; speedup vs baseline: 1.2082x; 1.0590x over previous
//
#include <hip/hip_runtime.h>
#include <hip/hip_fp16.h>

// Problem constants (from reference)
#define NN 50000
#define EE 800000
#define MAXDEG 64            // Poisson(16) max degree; P(deg>64) ~ 1e-18
#define NODE_BLOCKS 782      // ceil(50000/64)
#define EDGE_BLOCKS 1563     // ceil(800000/512), 2 edges/thread
#define TOTAL_BLOCKS 2345    // interleaved: bid%3==0 -> node, else edge

typedef _Float16 f16x8 __attribute__((ext_vector_type(8)));
typedef float    f32x4 __attribute__((ext_vector_type(4)));

union F4H { float4 f4; __half2 h2[4]; };

// ---------------------------------------------------------------------------
// Heterogeneous prep+build kernel. Roles interleaved in dispatch order so
// every CU co-schedules both from t=0:
//   edge role (2/3 of blocks): 512 edges, returning atomicAdd cursor +
//     scattered store. Slim (few VGPRs) -> high occupancy, hides atomic RTT.
//   node role (1/3 of blocks): W->LDS f16 fragment-order, MFMA linears
//     (16 nodes x 128 cols per wave), qv fp16 pack. Uses VALU/MFMA/HBM —
//     resources the edge role leaves idle.
// ---------------------------------------------------------------------------
__global__ __launch_bounds__(256) void prep_build_kernel(
    const float* __restrict__ feat,
    const float* __restrict__ Wk, const float* __restrict__ bk,
    const float* __restrict__ Ws, const float* __restrict__ bs,
    const float* __restrict__ q, const float* __restrict__ v,
    const int* __restrict__ src, const int* __restrict__ dst,
    float* __restrict__ kdst, float* __restrict__ skip,
    __half2* __restrict__ qv, int* __restrict__ count,
    int* __restrict__ sorted_src)
{
    __shared__ f16x8 sFrag[16 * 64];   // 16 KB (node role only)

    int tid = threadIdx.x, bid = blockIdx.x;

    if (bid % 3 != 0) {
        // ---------------- edge role ----------------
        int ebid  = bid - 1 - bid / 3;        // 0..EDGE_BLOCKS-1
        int ebase = ebid * 512 + tid * 2;     // EE % 2 == 0 -> all-or-nothing
        if (ebase < EE) {
            int2 es = *(const int2*)(src + ebase);
            int2 ed = *(const int2*)(dst + ebase);
            int p0 = atomicAdd(count + ed.x, 1);
            int p1 = atomicAdd(count + ed.y, 1);
            if (p0 < MAXDEG) sorted_src[ed.x * MAXDEG + p0] = es.x;
            if (p1 < MAXDEG) sorted_src[ed.y * MAXDEG + p1] = es.y;
        }
        return;
    }

    // ---------------- node role ----------------
    int nbid = bid / 3;                       // 0..NODE_BLOCKS-1
    int wave = tid >> 6, lane = tid & 63;

    // W -> LDS f16 fragment-order:
    // element (k, n): ktile = k>>5, lane = ((k>>3)&3)*16 + (n&15), j = k&7,
    // coltile = n>>4 (Wk: cols 0-63, Ws: cols 64-127)
    for (int i = tid; i < 4096; i += 256) {
        int k = i >> 6, nk = i & 63;
        int kt = k >> 5, j = k & 7;
        int lf = ((k >> 3) & 3) * 16 + (nk & 15);
        ((_Float16*)&sFrag[((nk >> 4) * 2 + kt) * 64 + lf])[j]       = (_Float16)Wk[i];
        ((_Float16*)&sFrag[((4 + (nk >> 4)) * 2 + kt) * 64 + lf])[j] = (_Float16)Ws[i];
    }

    __syncthreads();

    // MFMA linears. NN % 16 == 0 -> node tiles all-or-nothing
    int base16 = nbid * 64 + wave * 16;
    if (base16 < NN) {
        int m  = lane & 15;                   // A row (node) / D col key
        int kg = lane >> 4;                   // k-octet group
        const float* arow = feat + (size_t)(base16 + m) * 64 + kg * 8;
        float4 fa0 = *(const float4*)(arow + 0);
        float4 fa1 = *(const float4*)(arow + 4);
        float4 fa2 = *(const float4*)(arow + 32);
        float4 fa3 = *(const float4*)(arow + 36);
        f16x8 a0 = { (_Float16)fa0.x,(_Float16)fa0.y,(_Float16)fa0.z,(_Float16)fa0.w,
                     (_Float16)fa1.x,(_Float16)fa1.y,(_Float16)fa1.z,(_Float16)fa1.w };
        f16x8 a1 = { (_Float16)fa2.x,(_Float16)fa2.y,(_Float16)fa2.z,(_Float16)fa2.w,
                     (_Float16)fa3.x,(_Float16)fa3.y,(_Float16)fa3.z,(_Float16)fa3.w };

        f32x4 acc0={0,0,0,0}, acc1={0,0,0,0}, acc2={0,0,0,0}, acc3={0,0,0,0};
        f32x4 acc4={0,0,0,0}, acc5={0,0,0,0}, acc6={0,0,0,0}, acc7={0,0,0,0};

#define COLT(c, ACC) { \
        f16x8 b0 = sFrag[((c)*2 + 0) * 64 + lane]; \
        f16x8 b1 = sFrag[((c)*2 + 1) * 64 + lane]; \
        ACC = __builtin_amdgcn_mfma_f32_16x16x32_f16(a0, b0, ACC, 0, 0, 0); \
        ACC = __builtin_amdgcn_mfma_f32_16x16x32_f16(a1, b1, ACC, 0, 0, 0); }

        COLT(0, acc0) COLT(1, acc1) COLT(2, acc2) COLT(3, acc3)
        COLT(4, acc4) COLT(5, acc5) COLT(6, acc6) COLT(7, acc7)
#undef COLT

        int rbase = base16 + (lane >> 4) * 4;   // D row = (lane>>4)*4 + reg

#define STOREC(P, COFF, BIAS, ACC) { \
        int col = (COFF) + m; float bb = BIAS[col]; \
        P[(size_t)(rbase + 0) * 64 + col] = ACC[0] + bb; \
        P[(size_t)(rbase + 1) * 64 + col] = ACC[1] + bb; \
        P[(size_t)(rbase + 2) * 64 + col] = ACC[2] + bb; \
        P[(size_t)(rbase + 3) * 64 + col] = ACC[3] + bb; }

        STOREC(kdst,  0, bk, acc0) STOREC(kdst, 16, bk, acc1)
        STOREC(kdst, 32, bk, acc2) STOREC(kdst, 48, bk, acc3)
        STOREC(skip,  0, bs, acc4) STOREC(skip, 16, bs, acc5)
        STOREC(skip, 32, bs, acc6) STOREC(skip, 48, bs, acc7)
#undef STOREC
    }

    // qv fp16 pack (16 half2 per thread)
    {
        size_t g0 = (size_t)nbid * 4096 + (size_t)tid * 16;
        int node = (int)(g0 >> 6);
        if (node < NN) {
            const float4* qp = (const float4*)(q + g0);
            const float4* vp = (const float4*)(v + g0);
            #pragma unroll
            for (int gI = 0; gI < 4; ++gI) {
                float4 qq = qp[gI], vv = vp[gI];
                F4H outw;
                outw.h2[0] = __floats2half2_rn(qq.x, vv.x);
                outw.h2[1] = __floats2half2_rn(qq.y, vv.y);
                outw.h2[2] = __floats2half2_rn(qq.z, vv.z);
                outw.h2[3] = __floats2half2_rn(qq.w, vv.w);
                *(float4*)(qv + g0 + gI * 4) = outw.f4;
            }
        }
    }
}

// ---------------------------------------------------------------------------
// Gather aggregation + epilogue. One 64-lane wave per node.
// Lane layout: g = lane>>4, w = lane&15 covers slots w*4..w*4+3.
// 8 edges per iteration (two streams per lane), 1-deep software prefetch.
// softmax shift-invariance -> no segment-max pass (scores are O(5)).
// ---------------------------------------------------------------------------
__global__ __launch_bounds__(256) void gather_finalize_kernel(
    const __half2* __restrict__ qv,        // [N,64] (q,v) pairs
    const float*   __restrict__ kdst,      // [N,64]
    const float*   __restrict__ skipb,     // [N,64]
    const int*     __restrict__ sorted_src,// [N,MAXDEG]
    const int*     __restrict__ deg,       // [N]
    const float*   __restrict__ Wg,        // [192]
    const float*   __restrict__ bg,
    const float*   __restrict__ gamma,
    const float*   __restrict__ beta,
    const float*   __restrict__ prelu_a,
    float* __restrict__ out, int n)
{
    int node = (blockIdx.x * 256 + threadIdx.x) >> 6;
    int lane = threadIdx.x & 63;
    if (node >= n) return;
    int g = lane >> 4;   // edge sub-stream
    int w = lane & 15;   // slot quartet index
    int slot = w * 4;

    // hoisted epilogue operands (overlap with the gather loop)
    float4 k4  = *(const float4*)(kdst  + (size_t)node * 64 + slot);
    float4 sk4 = *(const float4*)(skipb + (size_t)node * 64 + slot);
    float wg0a = Wg[slot],      wg1a = Wg[slot+1],      wg2a = Wg[slot+2],      wg3a = Wg[slot+3];
    float wg0b = Wg[64+slot],   wg1b = Wg[64+slot+1],   wg2b = Wg[64+slot+2],   wg3b = Wg[64+slot+3];
    float wg0c = Wg[128+slot],  wg1c = Wg[128+slot+1],  wg2c = Wg[128+slot+2],  wg3c = Wg[128+slot+3];
    float gm0 = gamma[slot], gm1 = gamma[slot+1], gm2 = gamma[slot+2], gm3 = gamma[slot+3];
    float bt0 = beta[slot],  bt1 = beta[slot+1],  bt2 = beta[slot+2],  bt3 = beta[slot+3];
    float bgv = bg[0];
    float al  = prelu_a[0];

    int dcount = deg[node];
    if (dcount > MAXDEG) dcount = MAXDEG;
    int s_all = (lane < dcount) ? sorted_src[(size_t)node * MAXDEG + lane] : 0;

    float den = 0.f;
    float acc0 = 0.f, acc1 = 0.f, acc2 = 0.f, acc3 = 0.f;

    int niter = (dcount + 7) >> 3;
    if (niter > 0) {
        int sA = __shfl(s_all, g);
        int sB = __shfl(s_all, 4 + g);
        F4H rA, rB;
        rA.f4 = *(const float4*)(qv + (size_t)sA * 64 + slot);
        rB.f4 = *(const float4*)(qv + (size_t)sB * 64 + slot);

        for (int it = 0; it < niter; ++it) {
            F4H cA = rA, cB = rB;
            int eA = it * 8 + g;
            int eB = it * 8 + 4 + g;
            if (it + 1 < niter) {
                int sA2 = __shfl(s_all, (it * 8 + 8 + g) & 63);
                int sB2 = __shfl(s_all, (it * 8 + 12 + g) & 63);
                rA.f4 = *(const float4*)(qv + (size_t)sA2 * 64 + slot);
                rB.f4 = *(const float4*)(qv + (size_t)sB2 * 64 + slot);
            }

            float2 a0 = __half22float2(cA.h2[0]);
            float2 a1 = __half22float2(cA.h2[1]);
            float2 a2 = __half22float2(cA.h2[2]);
            float2 a3 = __half22float2(cA.h2[3]);
            float pA = a0.x * k4.x + a1.x * k4.y + a2.x * k4.z + a3.x * k4.w;
            pA += __shfl_xor(pA, 1);
            pA += __shfl_xor(pA, 2);
            float exA = (eA < dcount) ? __expf(pA * 0.25f) : 0.f;
            den += exA;
            acc0 = fmaf(exA, a0.y, acc0);
            acc1 = fmaf(exA, a1.y, acc1);
            acc2 = fmaf(exA, a2.y, acc2);
            acc3 = fmaf(exA, a3.y, acc3);

            float2 b0 = __half22float2(cB.h2[0]);
            float2 b1 = __half22float2(cB.h2[1]);
            float2 b2 = __half22float2(cB.h2[2]);
            float2 b3 = __half22float2(cB.h2[3]);
            float pB = b0.x * k4.x + b1.x * k4.y + b2.x * k4.z + b3.x * k4.w;
            pB += __shfl_xor(pB, 1);
            pB += __shfl_xor(pB, 2);
            float exB = (eB < dcount) ? __expf(pB * 0.25f) : 0.f;
            den += exB;
            acc0 = fmaf(exB, b0.y, acc0);
            acc1 = fmaf(exB, b1.y, acc1);
            acc2 = fmaf(exB, b2.y, acc2);
            acc3 = fmaf(exB, b3.y, acc3);
        }
    }

    // reduce across the 4 edge-stream groups
    den  += __shfl_xor(den, 16);  den  += __shfl_xor(den, 32);
    acc0 += __shfl_xor(acc0, 16); acc0 += __shfl_xor(acc0, 32);
    acc1 += __shfl_xor(acc1, 16); acc1 += __shfl_xor(acc1, 32);
    acc2 += __shfl_xor(acc2, 16); acc2 += __shfl_xor(acc2, 32);
    acc3 += __shfl_xor(acc3, 16); acc3 += __shfl_xor(acc3, 32);

    float inv = (den > 0.f) ? 1.f / den : 0.f;
    float r0 = acc0 * inv, r1 = acc1 * inv, r2 = acc2 * inv, r3 = acc3 * inv;

    // gate: sigmoid([skip, rst, skip-rst] @ Wg + bg)
    float gp = sk4.x * wg0a + r0 * wg0b + (sk4.x - r0) * wg0c
             + sk4.y * wg1a + r1 * wg1b + (sk4.y - r1) * wg1c
             + sk4.z * wg2a + r2 * wg2b + (sk4.z - r2) * wg2c
             + sk4.w * wg3a + r3 * wg3b + (sk4.w - r3) * wg3c;
    gp += __shfl_xor(gp, 1);
    gp += __shfl_xor(gp, 2);
    gp += __shfl_xor(gp, 4);
    gp += __shfl_xor(gp, 8);
    float gate = 1.f / (1.f + __expf(-(gp + bgv)));

    float m0 = gate * sk4.x + (1.f - gate) * r0;
    float m1 = gate * sk4.y + (1.f - gate) * r1;
    float m2 = gate * sk4.z + (1.f - gate) * r2;
    float m3 = gate * sk4.w + (1.f - gate) * r3;

    // LayerNorm over 64
    float mu = m0 + m1 + m2 + m3;
    mu += __shfl_xor(mu, 1); mu += __shfl_xor(mu, 2);
    mu += __shfl_xor(mu, 4); mu += __shfl_xor(mu, 8);
    mu *= (1.f / 64.f);
    float d0 = m0 - mu, d1 = m1 - mu, d2 = m2 - mu, d3 = m3 - mu;
    float var = d0 * d0 + d1 * d1 + d2 * d2 + d3 * d3;
    var += __shfl_xor(var, 1); var += __shfl_xor(var, 2);
    var += __shfl_xor(var, 4); var += __shfl_xor(var, 8);
    var *= (1.f / 64.f);
    float rs = rsqrtf(var + 1e-5f);

    float y0 = d0 * rs * gm0 + bt0;
    float y1 = d1 * rs * gm1 + bt1;
    float y2 = d2 * rs * gm2 + bt2;
    float y3 = d3 * rs * gm3 + bt3;
    y0 = (y0 >= 0.f) ? y0 : al * y0;
    y1 = (y1 >= 0.f) ? y1 : al * y1;
    y2 = (y2 >= 0.f) ? y2 : al * y2;
    y3 = (y3 >= 0.f) ? y3 : al * y3;

    if (g == 0) {
        float4 o; o.x = y0; o.y = y1; o.z = y2; o.w = y3;
        *(float4*)(out + (size_t)node * 64 + slot) = o;
    }
}

// ---------------------------------------------------------------------------
extern "C" void kernel_launch(void* const* d_in, const int* in_sizes, int n_in,
                              void* d_out, int out_size, void* d_ws, size_t ws_size,
                              hipStream_t stream)
{
    const float* q_src  = (const float*)d_in[0];
    const float* v_src  = (const float*)d_in[1];
    const float* feat   = (const float*)d_in[2];
    const int*   src    = (const int*)d_in[3];
    const int*   dst    = (const int*)d_in[4];
    const float* Wk     = (const float*)d_in[5];
    const float* bk     = (const float*)d_in[6];
    const float* Wskip  = (const float*)d_in[7];
    const float* bskip  = (const float*)d_in[8];
    const float* Wgate  = (const float*)d_in[9];
    const float* bgate  = (const float*)d_in[10];
    const float* ln_g   = (const float*)d_in[11];
    const float* ln_b   = (const float*)d_in[12];
    const float* prelu  = (const float*)d_in[13];

    float* out = (float*)d_out;

    // workspace layout
    char* ws = (char*)d_ws;
    const size_t A = (size_t)NN * 64 * 4;            // 12.8 MB unit
    float*    kdst       = (float*)(ws);             // N*64 f
    float*    skip       = (float*)(ws + A);         // N*64 f
    int*      sorted_src = (int*)  (ws + 2 * A);     // N*64 i
    __half2*  qv         = (__half2*)(ws + 3 * A);   // N*64 h2
    int*      count      = (int*)  (ws + 4 * A);     // N i

    hipMemsetAsync(count, 0, (size_t)NN * 4, stream);

    prep_build_kernel<<<TOTAL_BLOCKS, 256, 0, stream>>>(
        feat, Wk, bk, Wskip, bskip, q_src, v_src, src, dst,
        kdst, skip, qv, count, sorted_src);

    int gblk = (NN * 64 + 255) / 256;   // one wave per node
    gather_finalize_kernel<<<gblk, 256, 0, stream>>>(qv, kdst, skip,
                                                     sorted_src, count,
                                                     Wgate, bgate, ln_g, ln_b,
                                                     prelu, out, NN);
}